// Round 1
// baseline (806.211 us; speedup 1.0000x reference)
//
#include <hip/hip_runtime.h>
#include <math.h>

// Problem constants (B,T,S,D fixed by the reference).
#define BN 8
#define TT 2048
#define SS 2048
#define DD 256
#define NSEG 32
#define SEGLEN 64   // TT / NSEG

// ---------------------------------------------------------------------------
// K1: align[b,t,s] = dot(source[b,t,:], mem[b,s,:])
// 128x128 output tile per block, 8x8 micro-tile per thread, k-chunks of 8.
// Writes raw logits into the align_vectors region of d_out (scratch reuse).
// ---------------------------------------------------------------------------
__global__ __launch_bounds__(256) void k1_gemm_align(
    const float* __restrict__ src, const float* __restrict__ mem,
    float* __restrict__ alignb)
{
    __shared__ float As[8][128];
    __shared__ float Bs[8][128];
    const int b  = blockIdx.z;
    const int t0 = blockIdx.y * 128;
    const int s0 = blockIdx.x * 128;
    const int tid = threadIdx.x;
    const int tx = tid & 15, ty = tid >> 4;

    float acc[8][8];
#pragma unroll
    for (int i = 0; i < 8; i++)
#pragma unroll
        for (int j = 0; j < 8; j++) acc[i][j] = 0.f;

    const float* aBase = src + ((size_t)b * TT + t0) * DD;
    const float* bBase = mem + ((size_t)b * SS + s0) * DD;
    const int lr = tid >> 1;        // 0..127 (row within tile)
    const int lk = (tid & 1) * 4;   // 0 or 4 (k sub-chunk)

    for (int k0 = 0; k0 < DD; k0 += 8) {
        float4 av = *(const float4*)(aBase + (size_t)lr * DD + k0 + lk);
        float4 bv = *(const float4*)(bBase + (size_t)lr * DD + k0 + lk);
        __syncthreads();   // previous iteration's reads done
        As[lk + 0][lr] = av.x; As[lk + 1][lr] = av.y;
        As[lk + 2][lr] = av.z; As[lk + 3][lr] = av.w;
        Bs[lk + 0][lr] = bv.x; Bs[lk + 1][lr] = bv.y;
        Bs[lk + 2][lr] = bv.z; Bs[lk + 3][lr] = bv.w;
        __syncthreads();
#pragma unroll
        for (int k = 0; k < 8; k++) {
            float a[8], bb[8];
#pragma unroll
            for (int i = 0; i < 8; i++) a[i] = As[k][ty * 8 + i];
#pragma unroll
            for (int j = 0; j < 8; j++) bb[j] = Bs[k][tx * 8 + j];
#pragma unroll
            for (int i = 0; i < 8; i++)
#pragma unroll
                for (int j = 0; j < 8; j++)
                    acc[i][j] += a[i] * bb[j];
        }
    }

#pragma unroll
    for (int i = 0; i < 8; i++) {
        const int t = t0 + ty * 8 + i;
        float* row = alignb + ((size_t)b * TT + t) * SS + s0 + tx * 8;
        float4 v0 = {acc[i][0], acc[i][1], acc[i][2], acc[i][3]};
        float4 v1 = {acc[i][4], acc[i][5], acc[i][6], acc[i][7]};
        *(float4*)(row)     = v0;
        *(float4*)(row + 4) = v1;
    }
}

// ---------------------------------------------------------------------------
// K2: rowmax[b*T+t] = max over valid s (s < len[b]) of align[b,t,s]
// One block (256 threads) per row.
// ---------------------------------------------------------------------------
__global__ __launch_bounds__(256) void k2_rowmax(
    const float* __restrict__ alignb, const int* __restrict__ lens,
    float* __restrict__ rowmax)
{
    const int row = blockIdx.x;        // b*TT + t
    const int b = row >> 11;           // TT = 2048
    const int len = lens[b];
    const float* r = alignb + (size_t)row * SS;
    float m = -INFINITY;
    for (int s = threadIdx.x; s < len; s += 256) m = fmaxf(m, r[s]);
#pragma unroll
    for (int off = 32; off > 0; off >>= 1) m = fmaxf(m, __shfl_down(m, off, 64));
    __shared__ float w[4];
    if ((threadIdx.x & 63) == 0) w[threadIdx.x >> 6] = m;
    __syncthreads();
    if (threadIdx.x == 0)
        rowmax[row] = fmaxf(fmaxf(w[0], w[1]), fmaxf(w[2], w[3]));
}

// ---------------------------------------------------------------------------
// K3: per-(b,seg,s) sum over the segment's 64 rows of e = exp(align - max)
// ---------------------------------------------------------------------------
__global__ __launch_bounds__(256) void k3_segsum(
    const float* __restrict__ alignb, const float* __restrict__ rowmax,
    const int* __restrict__ lens, float* __restrict__ segsum)
{
    const int b = blockIdx.z, seg = blockIdx.y;
    const int s = blockIdx.x * 256 + threadIdx.x;
    const bool valid = s < lens[b];
    const float* base = alignb + ((size_t)b * TT + seg * SEGLEN) * SS + s;
    const float* rm = rowmax + b * TT + seg * SEGLEN;
    float sum = 0.f;
    for (int r = 0; r < SEGLEN; r++) {
        float e = valid ? expf(base[(size_t)r * SS] - rm[r]) : 0.f;
        sum += e;
    }
    segsum[((size_t)b * NSEG + seg) * SS + s] = sum;
}

// ---------------------------------------------------------------------------
// K4: exclusive prefix over the 32 segments, per (b,s) column, in place.
// ---------------------------------------------------------------------------
__global__ __launch_bounds__(256) void k4_prefix(float* __restrict__ segsum)
{
    const int b = blockIdx.y;
    const int s = blockIdx.x * 256 + threadIdx.x;
    float run = 0.f;
    for (int seg = 0; seg < NSEG; seg++) {
        const size_t idx = ((size_t)b * NSEG + seg) * SS + s;
        float v = segsum[idx];
        segsum[idx] = run;
        run += v;
    }
}

// ---------------------------------------------------------------------------
// K5: in-segment scan. unnorm = e / (penalty + 1e-20) written in place over
// the logits; per-row partial sums (8 chunks of 256 columns) to ws.
// penalty[t=0] = 1 exactly (reference concatenates ones).
// ---------------------------------------------------------------------------
__global__ __launch_bounds__(256) void k5_scan(
    float* __restrict__ alignb, const float* __restrict__ rowmax,
    const float* __restrict__ segsum, const int* __restrict__ lens,
    float* __restrict__ partial)
{
    const int b = blockIdx.z, seg = blockIdx.y, chunk = blockIdx.x;
    const int s = chunk * 256 + threadIdx.x;
    const bool valid = s < lens[b];
    float psum = segsum[((size_t)b * NSEG + seg) * SS + s];
    __shared__ float wsum[4];
    for (int r = 0; r < SEGLEN; r++) {
        const int t = seg * SEGLEN + r;
        const size_t idx = ((size_t)b * TT + t) * SS + s;
        const float m = rowmax[b * TT + t];
        float e = valid ? expf(alignb[idx] - m) : 0.f;
        float div = (t == 0) ? 1.0f : (psum + 1e-20f);
        float u = e / div;
        psum += e;
        alignb[idx] = u;
        // block-reduce u -> one partial per (row, chunk)
        float red = u;
#pragma unroll
        for (int off = 32; off > 0; off >>= 1) red += __shfl_down(red, off, 64);
        if ((threadIdx.x & 63) == 0) wsum[threadIdx.x >> 6] = red;
        __syncthreads();
        if (threadIdx.x == 0)
            partial[((size_t)b * TT + t) * 8 + chunk] =
                wsum[0] + wsum[1] + wsum[2] + wsum[3];
        __syncthreads();
    }
}

// ---------------------------------------------------------------------------
// K6: c[b,t,:] = sum_s (unnorm * inv_rowsum) * mem[b,s,:]
// Fuses the row normalization and the final align_vectors write (in place).
// Block: 32 t-rows x all 256 d-cols; threads (tx=64 d-groups x ty=4).
// ---------------------------------------------------------------------------
__global__ __launch_bounds__(256) void k6_context(
    float* __restrict__ alignb, const float* __restrict__ mem,
    const float* __restrict__ partial, float* __restrict__ cbuf)
{
    const int b = blockIdx.y;
    const int t0 = blockIdx.x * 32;
    const int tid = threadIdx.x;
    const int tx = tid & 63, ty = tid >> 6;

    __shared__ float inv[32];
    __shared__ __align__(16) float mT[32][256];
    __shared__ float aT[32][32];

    if (tid < 32) {
        const float* p = partial + ((size_t)b * TT + t0 + tid) * 8;
        float ssum = 0.f;
#pragma unroll
        for (int i = 0; i < 8; i++) ssum += p[i];
        inv[tid] = 1.0f / ssum;
    }
    __syncthreads();

    float4 acc[8];
#pragma unroll
    for (int i = 0; i < 8; i++) acc[i] = make_float4(0.f, 0.f, 0.f, 0.f);

    for (int s0 = 0; s0 < SS; s0 += 32) {
        __syncthreads();
        // stage memory_bank tile [32][256]
#pragma unroll
        for (int it = 0; it < 8; it++) {
            int f = tid + it * 256;          // float4 index 0..2047
            int sr = f >> 6, col = (f & 63) * 4;
            *(float4*)&mT[sr][col] =
                *(const float4*)(mem + ((size_t)b * SS + s0 + sr) * DD + col);
        }
        // stage a tile [32][32]: normalize + write final align_vectors back
#pragma unroll
        for (int rep = 0; rep < 4; rep++) {
            int idx = tid + rep * 256;
            int r = idx >> 5, c = idx & 31;
            size_t g = ((size_t)b * TT + t0 + r) * SS + s0 + c;
            float v = alignb[g] * inv[r];
            alignb[g] = v;
            aT[r][c] = v;
        }
        __syncthreads();
#pragma unroll
        for (int s = 0; s < 32; s++) {
            float4 m4 = *(const float4*)&mT[s][tx * 4];
#pragma unroll
            for (int r4 = 0; r4 < 8; r4++) {
                float a = aT[ty + r4 * 4][s];
                acc[r4].x += a * m4.x; acc[r4].y += a * m4.y;
                acc[r4].z += a * m4.z; acc[r4].w += a * m4.w;
            }
        }
    }
#pragma unroll
    for (int r4 = 0; r4 < 8; r4++) {
        const int t = t0 + ty + r4 * 4;
        *(float4*)(cbuf + ((size_t)b * TT + t) * DD + tx * 4) = acc[r4];
    }
}

// ---------------------------------------------------------------------------
// K7: attn_h = tanh([c, source] @ W_out), W_out is [2D][D] row-major.
// Same block structure as K6; k-loop over 512 in chunks of 32.
// ---------------------------------------------------------------------------
__global__ __launch_bounds__(256) void k7_out(
    const float* __restrict__ cbuf, const float* __restrict__ src,
    const float* __restrict__ W, float* __restrict__ attn)
{
    const int b = blockIdx.y;
    const int t0 = blockIdx.x * 32;
    const int tid = threadIdx.x;
    const int tx = tid & 63, ty = tid >> 6;

    __shared__ __align__(16) float wT[32][256];
    __shared__ float xT[32][32];

    float4 acc[8];
#pragma unroll
    for (int i = 0; i < 8; i++) acc[i] = make_float4(0.f, 0.f, 0.f, 0.f);

    for (int k0 = 0; k0 < 2 * DD; k0 += 32) {
        __syncthreads();
#pragma unroll
        for (int it = 0; it < 8; it++) {
            int f = tid + it * 256;
            int kr = f >> 6, col = (f & 63) * 4;
            *(float4*)&wT[kr][col] =
                *(const float4*)(W + (size_t)(k0 + kr) * DD + col);
        }
#pragma unroll
        for (int rep = 0; rep < 4; rep++) {
            int idx = tid + rep * 256;
            int r = idx >> 5, c = idx & 31;
            int k = k0 + c;
            float x = (k < DD)
                ? cbuf[((size_t)b * TT + t0 + r) * DD + k]
                : src[((size_t)b * TT + t0 + r) * DD + (k - DD)];
            xT[r][c] = x;
        }
        __syncthreads();
#pragma unroll
        for (int kk = 0; kk < 32; kk++) {
            float4 w4 = *(const float4*)&wT[kk][tx * 4];
#pragma unroll
            for (int r4 = 0; r4 < 8; r4++) {
                float x = xT[ty + r4 * 4][kk];
                acc[r4].x += x * w4.x; acc[r4].y += x * w4.y;
                acc[r4].z += x * w4.z; acc[r4].w += x * w4.w;
            }
        }
    }
#pragma unroll
    for (int r4 = 0; r4 < 8; r4++) {
        const int t = t0 + ty + r4 * 4;
        float4 o;
        o.x = tanhf(acc[r4].x); o.y = tanhf(acc[r4].y);
        o.z = tanhf(acc[r4].z); o.w = tanhf(acc[r4].w);
        *(float4*)(attn + ((size_t)b * TT + t) * DD + tx * 4) = o;
    }
}

// ---------------------------------------------------------------------------
extern "C" void kernel_launch(void* const* d_in, const int* in_sizes, int n_in,
                              void* d_out, int out_size, void* d_ws, size_t ws_size,
                              hipStream_t stream)
{
    const float* src  = (const float*)d_in[0];   // [B,T,D]
    const float* mem  = (const float*)d_in[1];   // [B,S,D]
    const float* Wout = (const float*)d_in[2];   // [2D,D]
    const int*   lens = (const int*)d_in[3];     // [B]

    float* out    = (float*)d_out;
    float* attn   = out;                               // [B,T,D]
    float* alignb = out + (size_t)BN * TT * DD;        // [B,T,S] (scratch->final)

    float* rowmax  = (float*)d_ws;                     // B*T
    float* partial = rowmax + (size_t)BN * TT;         // B*T*8
    float* segsum  = partial + (size_t)BN * TT * 8;    // B*NSEG*S
    float* cbuf    = segsum + (size_t)BN * NSEG * SS;  // B*T*D

    k1_gemm_align<<<dim3(SS / 128, TT / 128, BN), 256, 0, stream>>>(src, mem, alignb);
    k2_rowmax<<<dim3(BN * TT), 256, 0, stream>>>(alignb, lens, rowmax);
    k3_segsum<<<dim3(SS / 256, NSEG, BN), 256, 0, stream>>>(alignb, rowmax, lens, segsum);
    k4_prefix<<<dim3(SS / 256, BN), 256, 0, stream>>>(segsum);
    k5_scan<<<dim3(SS / 256, NSEG, BN), 256, 0, stream>>>(alignb, rowmax, segsum, lens, partial);
    k6_context<<<dim3(TT / 32, BN), 256, 0, stream>>>(alignb, mem, partial, cbuf);
    k7_out<<<dim3(TT / 32, BN), 256, 0, stream>>>(cbuf, src, Wout, attn);
}

// Round 3
// 767.560 us; speedup vs baseline: 1.0504x; 1.0504x over previous
//
#include <hip/hip_runtime.h>
#include <math.h>

// Problem constants (B,T,S,D fixed by the reference).
#define BN 8
#define TT 2048
#define SS 2048
#define DD 256
#define NSEG 32
#define SEGLEN 64   // TT / NSEG

typedef __attribute__((ext_vector_type(8))) short short8;
typedef __attribute__((ext_vector_type(4))) float floatx4;

__device__ __forceinline__ unsigned short f2bf_rne(float f) {
    unsigned int u = __float_as_uint(f);
    u = (u + 0x7FFFu + ((u >> 16) & 1u)) >> 16;
    return (unsigned short)u;
}
__device__ __forceinline__ float bf2f(unsigned short h) {
    return __uint_as_float(((unsigned int)h) << 16);
}

// ---------------------------------------------------------------------------
// K1: align[b,t,s] = dot(source[b,t,:], mem[b,s,:])
// 128x128 output tile per block, 8x8 micro-tile per thread, k-chunks of 8.
// ---------------------------------------------------------------------------
__global__ __launch_bounds__(256) void k1_gemm_align(
    const float* __restrict__ src, const float* __restrict__ mem,
    float* __restrict__ alignb)
{
    __shared__ float As[8][128];
    __shared__ float Bs[8][128];
    const int b  = blockIdx.z;
    const int t0 = blockIdx.y * 128;
    const int s0 = blockIdx.x * 128;
    const int tid = threadIdx.x;
    const int tx = tid & 15, ty = tid >> 4;

    float acc[8][8];
#pragma unroll
    for (int i = 0; i < 8; i++)
#pragma unroll
        for (int j = 0; j < 8; j++) acc[i][j] = 0.f;

    const float* aBase = src + ((size_t)b * TT + t0) * DD;
    const float* bBase = mem + ((size_t)b * SS + s0) * DD;
    const int lr = tid >> 1;        // 0..127 (row within tile)
    const int lk = (tid & 1) * 4;   // 0 or 4 (k sub-chunk)

    for (int k0 = 0; k0 < DD; k0 += 8) {
        float4 av = *(const float4*)(aBase + (size_t)lr * DD + k0 + lk);
        float4 bv = *(const float4*)(bBase + (size_t)lr * DD + k0 + lk);
        __syncthreads();   // previous iteration's reads done
        As[lk + 0][lr] = av.x; As[lk + 1][lr] = av.y;
        As[lk + 2][lr] = av.z; As[lk + 3][lr] = av.w;
        Bs[lk + 0][lr] = bv.x; Bs[lk + 1][lr] = bv.y;
        Bs[lk + 2][lr] = bv.z; Bs[lk + 3][lr] = bv.w;
        __syncthreads();
#pragma unroll
        for (int k = 0; k < 8; k++) {
            float a[8], bb[8];
#pragma unroll
            for (int i = 0; i < 8; i++) a[i] = As[k][ty * 8 + i];
#pragma unroll
            for (int j = 0; j < 8; j++) bb[j] = Bs[k][tx * 8 + j];
#pragma unroll
            for (int i = 0; i < 8; i++)
#pragma unroll
                for (int j = 0; j < 8; j++)
                    acc[i][j] += a[i] * bb[j];
        }
    }

#pragma unroll
    for (int i = 0; i < 8; i++) {
        const int t = t0 + ty * 8 + i;
        float* row = alignb + ((size_t)b * TT + t) * SS + s0 + tx * 8;
        float4 v0 = {acc[i][0], acc[i][1], acc[i][2], acc[i][3]};
        float4 v1 = {acc[i][4], acc[i][5], acc[i][6], acc[i][7]};
        *(float4*)(row)     = v0;
        *(float4*)(row + 4) = v1;
    }
}

// ---------------------------------------------------------------------------
// K2: rowmax[b*T+t] = max over valid s (s < len[b]) of align[b,t,s]
// ---------------------------------------------------------------------------
__global__ __launch_bounds__(256) void k2_rowmax(
    const float* __restrict__ alignb, const int* __restrict__ lens,
    float* __restrict__ rowmax)
{
    const int row = blockIdx.x;        // b*TT + t
    const int b = row >> 11;           // TT = 2048
    const int len = lens[b];
    const float* r = alignb + (size_t)row * SS;
    float m = -INFINITY;
    for (int s = threadIdx.x; s < len; s += 256) m = fmaxf(m, r[s]);
#pragma unroll
    for (int off = 32; off > 0; off >>= 1) m = fmaxf(m, __shfl_down(m, off, 64));
    __shared__ float w[4];
    if ((threadIdx.x & 63) == 0) w[threadIdx.x >> 6] = m;
    __syncthreads();
    if (threadIdx.x == 0)
        rowmax[row] = fmaxf(fmaxf(w[0], w[1]), fmaxf(w[2], w[3]));
}

// ---------------------------------------------------------------------------
// K3: per-(b,seg,s) sum over the segment's 64 rows of e = exp(align - max)
// ---------------------------------------------------------------------------
__global__ __launch_bounds__(256) void k3_segsum(
    const float* __restrict__ alignb, const float* __restrict__ rowmax,
    const int* __restrict__ lens, float* __restrict__ segsum)
{
    const int b = blockIdx.z, seg = blockIdx.y;
    const int s = blockIdx.x * 256 + threadIdx.x;
    const bool valid = s < lens[b];
    const float* base = alignb + ((size_t)b * TT + seg * SEGLEN) * SS + s;
    const float* rm = rowmax + b * TT + seg * SEGLEN;
    float sum = 0.f;
    for (int r = 0; r < SEGLEN; r++) {
        float e = valid ? expf(base[(size_t)r * SS] - rm[r]) : 0.f;
        sum += e;
    }
    segsum[((size_t)b * NSEG + seg) * SS + s] = sum;
}

// ---------------------------------------------------------------------------
// K4: exclusive prefix over the 32 segments, per (b,s) column, in place.
// ---------------------------------------------------------------------------
__global__ __launch_bounds__(256) void k4_prefix(float* __restrict__ segsum)
{
    const int b = blockIdx.y;
    const int s = blockIdx.x * 256 + threadIdx.x;
    float run = 0.f;
    for (int seg = 0; seg < NSEG; seg++) {
        const size_t idx = ((size_t)b * NSEG + seg) * SS + s;
        float v = segsum[idx];
        segsum[idx] = run;
        run += v;
    }
}

// ---------------------------------------------------------------------------
// K5: in-segment scan. unnorm = e / (penalty + 1e-20) written in place over
// the logits; per-row partial sums (8 chunks of 256 columns) to ws.
// ---------------------------------------------------------------------------
__global__ __launch_bounds__(256) void k5_scan(
    float* __restrict__ alignb, const float* __restrict__ rowmax,
    const float* __restrict__ segsum, const int* __restrict__ lens,
    float* __restrict__ partial)
{
    const int b = blockIdx.z, seg = blockIdx.y, chunk = blockIdx.x;
    const int s = chunk * 256 + threadIdx.x;
    const bool valid = s < lens[b];
    float psum = segsum[((size_t)b * NSEG + seg) * SS + s];
    __shared__ float wsum[4];
    for (int r = 0; r < SEGLEN; r++) {
        const int t = seg * SEGLEN + r;
        const size_t idx = ((size_t)b * TT + t) * SS + s;
        const float m = rowmax[b * TT + t];
        float e = valid ? expf(alignb[idx] - m) : 0.f;
        float div = (t == 0) ? 1.0f : (psum + 1e-20f);
        float u = e / div;
        psum += e;
        alignb[idx] = u;
        float red = u;
#pragma unroll
        for (int off = 32; off > 0; off >>= 1) red += __shfl_down(red, off, 64);
        if ((threadIdx.x & 63) == 0) wsum[threadIdx.x >> 6] = red;
        __syncthreads();
        if (threadIdx.x == 0)
            partial[((size_t)b * TT + t) * 8 + chunk] =
                wsum[0] + wsum[1] + wsum[2] + wsum[3];
        __syncthreads();
    }
}

// ---------------------------------------------------------------------------
// KNORM: align_vectors = unnorm * (1/rowsum), in place.  Separate pass so K6
// never writes alignb (the Round-2 k6 had a cross-wave RAW race on it).
// One block per row; 2048 floats = 256 threads x 2 float4.
// ---------------------------------------------------------------------------
__global__ __launch_bounds__(256) void knorm(
    float* __restrict__ alignb, const float* __restrict__ partial)
{
    const int row = blockIdx.x;            // b*TT + t
    const float* p = partial + (size_t)row * 8;
    float ssum = 0.f;
#pragma unroll
    for (int i = 0; i < 8; i++) ssum += p[i];
    const float inv = 1.0f / ssum;
    float4* r = (float4*)(alignb + (size_t)row * SS);
    const int tid = threadIdx.x;
#pragma unroll
    for (int i = 0; i < 2; i++) {
        float4 v = r[tid + i * 256];
        v.x *= inv; v.y *= inv; v.z *= inv; v.w *= inv;
        r[tid + i * 256] = v;
    }
}

// ---------------------------------------------------------------------------
// K6pre: pre-swizzle memory_bank into MFMA B-fragment layout, split bf16
// hi/lo.  Fragment for 16x16x32: lane holds B[k=quad*8+j][n=lane&15].
// Index: frag[(((b*64 + c)*16 + dt)*64 + lane)*8 + j]
//   where c = s-chunk (32 wide), dt = d-tile (16 wide).
// ---------------------------------------------------------------------------
__global__ __launch_bounds__(256) void k6pre(
    const float* __restrict__ mem, unsigned short* __restrict__ mhi,
    unsigned short* __restrict__ mlo)
{
    const int gid = blockIdx.x * 256 + threadIdx.x;  // (b,c,dt,lane)
    const int lane = gid & 63;
    const int dt   = (gid >> 6) & 15;
    const int c    = (gid >> 10) & 63;
    const int b    = gid >> 16;
    const int quad = lane >> 4, n = lane & 15;
    const int s = c * 32 + quad * 8;
    const int d = dt * 16 + n;
    const float* srcp = mem + ((size_t)b * SS + s) * DD + d;
    short8 hi, lo;
#pragma unroll
    for (int j = 0; j < 8; j++) {
        float f = srcp[(size_t)j * DD];
        unsigned short h = f2bf_rne(f);
        hi[j] = (short)h;
        lo[j] = (short)f2bf_rne(f - bf2f(h));
    }
    *(short8*)(mhi + (size_t)gid * 8) = hi;
    *(short8*)(mlo + (size_t)gid * 8) = lo;
}

// ---------------------------------------------------------------------------
// K6: c[b,t,:] = sum_s align_vectors[b,t,s] * mem[b,s,:]  via split-bf16 MFMA
// (a_hi*b_hi + a_lo*b_hi + a_hi*b_lo), fp32 accumulate.  READ-ONLY on alignb
// (already normalized by knorm) — no races.  Block = 32 t x 256 d; 4 waves:
// wave = (h = t-half 16) x (dh = d-half 128).  No LDS, no barriers in the
// s-loop: each lane's global loads ARE its A-fragment (A[m=lane&15][k=quad*8+j]).
// Grid is (b, t-tile) so linear block id % 8 == b: pins each batch's B-frags
// to one XCD's L2 (locality heuristic only).
// ---------------------------------------------------------------------------
__global__ __launch_bounds__(256) void k6_context(
    const float* __restrict__ alignb, const unsigned short* __restrict__ mhi,
    const unsigned short* __restrict__ mlo, float* __restrict__ cbuf)
{
    const int b  = blockIdx.x;
    const int t0 = blockIdx.y * 32;
    const int tid  = threadIdx.x;
    const int wave = tid >> 6, lane = tid & 63;
    const int h  = wave & 1;      // t-half (16 rows)
    const int dh = wave >> 1;     // d-half (128 cols)
    const int quad = lane >> 4, m = lane & 15;

    const int rowl = h * 16 + m;                 // local t row 0..31
    const float* prow = alignb + ((size_t)(b * TT + t0 + rowl)) * SS + quad * 8;

    floatx4 acc[8];
#pragma unroll
    for (int i = 0; i < 8; i++) acc[i] = (floatx4)0.f;

    for (int c = 0; c < 64; c++) {               // s-chunks of 32
        float4 v0 = *(const float4*)(prow + c * 32);
        float4 v1 = *(const float4*)(prow + c * 32 + 4);
        float pv[8] = {v0.x, v0.y, v0.z, v0.w, v1.x, v1.y, v1.z, v1.w};
        short8 a_hi, a_lo;
#pragma unroll
        for (int j = 0; j < 8; j++) {
            unsigned short hh = f2bf_rne(pv[j]);
            a_hi[j] = (short)hh;
            a_lo[j] = (short)f2bf_rne(pv[j] - bf2f(hh));
        }
        const size_t fbase = (((size_t)(b * 64 + c) * 16 + dh * 8) * 64 + lane) * 8;
        const unsigned short* bh = mhi + fbase;
        const unsigned short* bl = mlo + fbase;
#pragma unroll
        for (int dt = 0; dt < 8; dt++) {
            short8 Bh = *(const short8*)(bh + dt * 512);
            short8 Bl = *(const short8*)(bl + dt * 512);
            acc[dt] = __builtin_amdgcn_mfma_f32_16x16x32_bf16(a_hi, Bh, acc[dt], 0, 0, 0);
            acc[dt] = __builtin_amdgcn_mfma_f32_16x16x32_bf16(a_lo, Bh, acc[dt], 0, 0, 0);
            acc[dt] = __builtin_amdgcn_mfma_f32_16x16x32_bf16(a_hi, Bl, acc[dt], 0, 0, 0);
        }
    }

    // C/D layout: col = lane&15 (d), row = quad*4 + reg (t)
#pragma unroll
    for (int dt = 0; dt < 8; dt++) {
        const int d = dh * 128 + dt * 16 + m;
#pragma unroll
        for (int reg = 0; reg < 4; reg++) {
            const int t = t0 + h * 16 + quad * 4 + reg;
            cbuf[((size_t)(b * TT + t)) * DD + d] = acc[dt][reg];
        }
    }
}

// ---------------------------------------------------------------------------
// K7: attn_h = tanh([c, source] @ W_out), W_out is [2D][D] row-major.
// ---------------------------------------------------------------------------
__global__ __launch_bounds__(256) void k7_out(
    const float* __restrict__ cbuf, const float* __restrict__ src,
    const float* __restrict__ W, float* __restrict__ attn)
{
    const int b = blockIdx.y;
    const int t0 = blockIdx.x * 32;
    const int tid = threadIdx.x;
    const int tx = tid & 63, ty = tid >> 6;

    __shared__ __align__(16) float wT[32][256];
    __shared__ float xT[32][32];

    float4 acc[8];
#pragma unroll
    for (int i = 0; i < 8; i++) acc[i] = make_float4(0.f, 0.f, 0.f, 0.f);

    for (int k0 = 0; k0 < 2 * DD; k0 += 32) {
        __syncthreads();
#pragma unroll
        for (int it = 0; it < 8; it++) {
            int f = tid + it * 256;
            int kr = f >> 6, col = (f & 63) * 4;
            *(float4*)&wT[kr][col] =
                *(const float4*)(W + (size_t)(k0 + kr) * DD + col);
        }
#pragma unroll
        for (int rep = 0; rep < 4; rep++) {
            int idx = tid + rep * 256;
            int r = idx >> 5, c = idx & 31;
            int k = k0 + c;
            float x = (k < DD)
                ? cbuf[((size_t)b * TT + t0 + r) * DD + k]
                : src[((size_t)b * TT + t0 + r) * DD + (k - DD)];
            xT[r][c] = x;
        }
        __syncthreads();
#pragma unroll
        for (int kk = 0; kk < 32; kk++) {
            float4 w4 = *(const float4*)&wT[kk][tx * 4];
#pragma unroll
            for (int r4 = 0; r4 < 8; r4++) {
                float x = xT[ty + r4 * 4][kk];
                acc[r4].x += x * w4.x; acc[r4].y += x * w4.y;
                acc[r4].z += x * w4.z; acc[r4].w += x * w4.w;
            }
        }
    }
#pragma unroll
    for (int r4 = 0; r4 < 8; r4++) {
        const int t = t0 + ty + r4 * 4;
        float4 o;
        o.x = tanhf(acc[r4].x); o.y = tanhf(acc[r4].y);
        o.z = tanhf(acc[r4].z); o.w = tanhf(acc[r4].w);
        *(float4*)(attn + ((size_t)b * TT + t) * DD + tx * 4) = o;
    }
}

// ---------------------------------------------------------------------------
extern "C" void kernel_launch(void* const* d_in, const int* in_sizes, int n_in,
                              void* d_out, int out_size, void* d_ws, size_t ws_size,
                              hipStream_t stream)
{
    const float* src  = (const float*)d_in[0];   // [B,T,D]
    const float* mem  = (const float*)d_in[1];   // [B,S,D]
    const float* Wout = (const float*)d_in[2];   // [2D,D]
    const int*   lens = (const int*)d_in[3];     // [B]

    float* out    = (float*)d_out;
    float* attn   = out;                               // [B,T,D]
    float* alignb = out + (size_t)BN * TT * DD;        // [B,T,S] (scratch->final)

    float* rowmax  = (float*)d_ws;                     // B*T
    float* partial = rowmax + (size_t)BN * TT;         // B*T*8
    float* segsum  = partial + (size_t)BN * TT * 8;    // B*NSEG*S
    float* cbuf    = segsum + (size_t)BN * NSEG * SS;  // B*T*D
    unsigned short* mhi = (unsigned short*)(cbuf + (size_t)BN * TT * DD);  // B*S*D bf16
    unsigned short* mlo = mhi + (size_t)BN * SS * DD;                      // B*S*D bf16

    k6pre<<<dim3(BN * 64 * 16 * 64 / 256), 256, 0, stream>>>(mem, mhi, mlo);
    k1_gemm_align<<<dim3(SS / 128, TT / 128, BN), 256, 0, stream>>>(src, mem, alignb);
    k2_rowmax<<<dim3(BN * TT), 256, 0, stream>>>(alignb, lens, rowmax);
    k3_segsum<<<dim3(SS / 256, NSEG, BN), 256, 0, stream>>>(alignb, rowmax, lens, segsum);
    k4_prefix<<<dim3(SS / 256, BN), 256, 0, stream>>>(segsum);
    k5_scan<<<dim3(SS / 256, NSEG, BN), 256, 0, stream>>>(alignb, rowmax, segsum, lens, partial);
    knorm<<<dim3(BN * TT), 256, 0, stream>>>(alignb, partial);
    k6_context<<<dim3(BN, TT / 32), 256, 0, stream>>>(alignb, mhi, mlo, cbuf);
    k7_out<<<dim3(TT / 32, BN), 256, 0, stream>>>(cbuf, src, Wout, attn);
}

// Round 4
// 682.133 us; speedup vs baseline: 1.1819x; 1.1252x over previous
//
#include <hip/hip_runtime.h>
#include <math.h>

// Problem constants (B,T,S,D fixed by the reference).
#define BN 8
#define TT 2048
#define SS 2048
#define DD 256
#define NSEG 32
#define SEGLEN 64   // TT / NSEG

typedef __attribute__((ext_vector_type(8))) short short8;
typedef __attribute__((ext_vector_type(4))) float floatx4;

__device__ __forceinline__ unsigned short f2bf_rne(float f) {
    unsigned int u = __float_as_uint(f);
    u = (u + 0x7FFFu + ((u >> 16) & 1u)) >> 16;
    return (unsigned short)u;
}
__device__ __forceinline__ float bf2f(unsigned short h) {
    return __uint_as_float(((unsigned int)h) << 16);
}

// ---------------------------------------------------------------------------
// KPRE: fp32 -> bf16 hi/lo split, row-major, for source (y=0) and memory_bank
// (y=1).  8 elements per thread.
// ---------------------------------------------------------------------------
__global__ __launch_bounds__(256) void kpre(
    const float* __restrict__ src, const float* __restrict__ mem,
    unsigned short* __restrict__ shi, unsigned short* __restrict__ slo,
    unsigned short* __restrict__ mhirm, unsigned short* __restrict__ mlorm)
{
    const float* in; unsigned short *oh, *ol;
    if (blockIdx.y == 0) { in = src; oh = shi; ol = slo; }
    else                 { in = mem; oh = mhirm; ol = mlorm; }
    const size_t base = ((size_t)blockIdx.x * 256 + threadIdx.x) * 8;
    float4 v0 = *(const float4*)(in + base);
    float4 v1 = *(const float4*)(in + base + 4);
    float f[8] = {v0.x, v0.y, v0.z, v0.w, v1.x, v1.y, v1.z, v1.w};
    short8 hv, lv;
#pragma unroll
    for (int j = 0; j < 8; j++) {
        unsigned short h = f2bf_rne(f[j]);
        hv[j] = (short)h;
        lv[j] = (short)f2bf_rne(f[j] - bf2f(h));
    }
    *(short8*)(oh + base) = hv;
    *(short8*)(ol + base) = lv;
}

// ---------------------------------------------------------------------------
// K1: align[b,t,s] = dot(src[b,t,:], mem[b,s,:]) via split-bf16 MFMA
// (a_hi*b_hi + a_lo*b_hi + a_hi*b_lo), fp32 accumulate.
// 128x128 tile per block; 4 waves in 2x2, each wave 64t x 64s (4x4 frags).
// No LDS, no barriers: A-frag A[m=lane&15][k=quad*8+j] and B-frag
// B[k=quad*8+j][n=lane&15] are both 16B-contiguous runs of the row-major
// bf16 buffers (row = t for A, row = s for B), loaded directly from global.
// ---------------------------------------------------------------------------
__global__ __launch_bounds__(256) void k1_mfma(
    const unsigned short* __restrict__ shi, const unsigned short* __restrict__ slo,
    const unsigned short* __restrict__ mhirm, const unsigned short* __restrict__ mlorm,
    float* __restrict__ alignb)
{
    const int b  = blockIdx.z;
    const int t0 = blockIdx.y * 128;
    const int s0 = blockIdx.x * 128;
    const int tid = threadIdx.x;
    const int wave = tid >> 6, lane = tid & 63;
    const int wt = wave & 1, wsb = wave >> 1;   // 2x2 wave grid
    const int quad = lane >> 4, r = lane & 15;

    // Row base pointers: A rows are t, B rows are s; both row-major [*][DD].
    const size_t aRow = ((size_t)(b * TT + t0 + wt * 64 + r)) * DD + quad * 8;
    const size_t bRow = ((size_t)(b * SS + s0 + wsb * 64 + r)) * DD + quad * 8;
    const unsigned short* pAh = shi + aRow;
    const unsigned short* pAl = slo + aRow;
    const unsigned short* pBh = mhirm + bRow;
    const unsigned short* pBl = mlorm + bRow;

    floatx4 acc[4][4];
#pragma unroll
    for (int i = 0; i < 4; i++)
#pragma unroll
        for (int j = 0; j < 4; j++) acc[i][j] = (floatx4)0.f;

    for (int kc = 0; kc < 8; kc++) {            // K = 256 in chunks of 32
        const int ko = kc * 32;
        short8 Ah[4], Al[4], Bh[4], Bl[4];
#pragma unroll
        for (int f = 0; f < 4; f++) {
            Ah[f] = *(const short8*)(pAh + (size_t)(f * 16) * DD + ko);
            Al[f] = *(const short8*)(pAl + (size_t)(f * 16) * DD + ko);
            Bh[f] = *(const short8*)(pBh + (size_t)(f * 16) * DD + ko);
            Bl[f] = *(const short8*)(pBl + (size_t)(f * 16) * DD + ko);
        }
#pragma unroll
        for (int mf = 0; mf < 4; mf++)
#pragma unroll
            for (int nf = 0; nf < 4; nf++) {
                acc[mf][nf] = __builtin_amdgcn_mfma_f32_16x16x32_bf16(
                    Ah[mf], Bh[nf], acc[mf][nf], 0, 0, 0);
                acc[mf][nf] = __builtin_amdgcn_mfma_f32_16x16x32_bf16(
                    Al[mf], Bh[nf], acc[mf][nf], 0, 0, 0);
                acc[mf][nf] = __builtin_amdgcn_mfma_f32_16x16x32_bf16(
                    Ah[mf], Bl[nf], acc[mf][nf], 0, 0, 0);
            }
    }

    // C/D layout: col = lane&15 (s), row = quad*4 + reg (t).
#pragma unroll
    for (int mf = 0; mf < 4; mf++)
#pragma unroll
        for (int reg = 0; reg < 4; reg++) {
            const int t = t0 + wt * 64 + mf * 16 + quad * 4 + reg;
            float* row = alignb + ((size_t)(b * TT + t)) * SS + s0 + wsb * 64 + r;
#pragma unroll
            for (int nf = 0; nf < 4; nf++)
                row[nf * 16] = acc[mf][nf][reg];
        }
}

// ---------------------------------------------------------------------------
// K2: rowmax[b*T+t] = max over valid s (s < len[b]) of align[b,t,s]
// ---------------------------------------------------------------------------
__global__ __launch_bounds__(256) void k2_rowmax(
    const float* __restrict__ alignb, const int* __restrict__ lens,
    float* __restrict__ rowmax)
{
    const int row = blockIdx.x;        // b*TT + t
    const int b = row >> 11;           // TT = 2048
    const int len = lens[b];
    const float* r = alignb + (size_t)row * SS;
    float m = -INFINITY;
    for (int s = threadIdx.x; s < len; s += 256) m = fmaxf(m, r[s]);
#pragma unroll
    for (int off = 32; off > 0; off >>= 1) m = fmaxf(m, __shfl_down(m, off, 64));
    __shared__ float w[4];
    if ((threadIdx.x & 63) == 0) w[threadIdx.x >> 6] = m;
    __syncthreads();
    if (threadIdx.x == 0)
        rowmax[row] = fmaxf(fmaxf(w[0], w[1]), fmaxf(w[2], w[3]));
}

// ---------------------------------------------------------------------------
// K3: per-(b,seg,s) sum over the segment's 64 rows of e = exp(align - max)
// ---------------------------------------------------------------------------
__global__ __launch_bounds__(256) void k3_segsum(
    const float* __restrict__ alignb, const float* __restrict__ rowmax,
    const int* __restrict__ lens, float* __restrict__ segsum)
{
    const int b = blockIdx.z, seg = blockIdx.y;
    const int s = blockIdx.x * 256 + threadIdx.x;
    const bool valid = s < lens[b];
    const float* base = alignb + ((size_t)b * TT + seg * SEGLEN) * SS + s;
    const float* rm = rowmax + b * TT + seg * SEGLEN;
    float sum = 0.f;
    for (int r = 0; r < SEGLEN; r++) {
        float e = valid ? expf(base[(size_t)r * SS] - rm[r]) : 0.f;
        sum += e;
    }
    segsum[((size_t)b * NSEG + seg) * SS + s] = sum;
}

// ---------------------------------------------------------------------------
// K4: exclusive prefix over the 32 segments, per (b,s) column, in place.
// ---------------------------------------------------------------------------
__global__ __launch_bounds__(256) void k4_prefix(float* __restrict__ segsum)
{
    const int b = blockIdx.y;
    const int s = blockIdx.x * 256 + threadIdx.x;
    float run = 0.f;
    for (int seg = 0; seg < NSEG; seg++) {
        const size_t idx = ((size_t)b * NSEG + seg) * SS + s;
        float v = segsum[idx];
        segsum[idx] = run;
        run += v;
    }
}

// ---------------------------------------------------------------------------
// K5: in-segment scan. unnorm = e / (penalty + 1e-20) written in place over
// the logits; per-row partial sums (8 chunks of 256 columns) to ws.
// ---------------------------------------------------------------------------
__global__ __launch_bounds__(256) void k5_scan(
    float* __restrict__ alignb, const float* __restrict__ rowmax,
    const float* __restrict__ segsum, const int* __restrict__ lens,
    float* __restrict__ partial)
{
    const int b = blockIdx.z, seg = blockIdx.y, chunk = blockIdx.x;
    const int s = chunk * 256 + threadIdx.x;
    const bool valid = s < lens[b];
    float psum = segsum[((size_t)b * NSEG + seg) * SS + s];
    __shared__ float wsum[4];
    for (int r = 0; r < SEGLEN; r++) {
        const int t = seg * SEGLEN + r;
        const size_t idx = ((size_t)b * TT + t) * SS + s;
        const float m = rowmax[b * TT + t];
        float e = valid ? expf(alignb[idx] - m) : 0.f;
        float div = (t == 0) ? 1.0f : (psum + 1e-20f);
        float u = e / div;
        psum += e;
        alignb[idx] = u;
        float red = u;
#pragma unroll
        for (int off = 32; off > 0; off >>= 1) red += __shfl_down(red, off, 64);
        if ((threadIdx.x & 63) == 0) wsum[threadIdx.x >> 6] = red;
        __syncthreads();
        if (threadIdx.x == 0)
            partial[((size_t)b * TT + t) * 8 + chunk] =
                wsum[0] + wsum[1] + wsum[2] + wsum[3];
        __syncthreads();
    }
}

// ---------------------------------------------------------------------------
// KNORM: align_vectors = unnorm * (1/rowsum), in place.  Separate pass so K6
// never writes alignb (Round-2 k6 had a cross-wave RAW race on it).
// ---------------------------------------------------------------------------
__global__ __launch_bounds__(256) void knorm(
    float* __restrict__ alignb, const float* __restrict__ partial)
{
    const int row = blockIdx.x;            // b*TT + t
    const float* p = partial + (size_t)row * 8;
    float ssum = 0.f;
#pragma unroll
    for (int i = 0; i < 8; i++) ssum += p[i];
    const float inv = 1.0f / ssum;
    float4* r = (float4*)(alignb + (size_t)row * SS);
    const int tid = threadIdx.x;
#pragma unroll
    for (int i = 0; i < 2; i++) {
        float4 v = r[tid + i * 256];
        v.x *= inv; v.y *= inv; v.z *= inv; v.w *= inv;
        r[tid + i * 256] = v;
    }
}

// ---------------------------------------------------------------------------
// K6pre: pre-swizzle memory_bank into MFMA B-fragment layout for K6 (B role:
// k = s, n = d), split bf16 hi/lo.  Lane holds B[k=quad*8+j][n=lane&15].
// Index: frag[(((b*64 + c)*16 + dt)*64 + lane)*8 + j]
//   where c = s-chunk (32 wide), dt = d-tile (16 wide).
// ---------------------------------------------------------------------------
__global__ __launch_bounds__(256) void k6pre(
    const float* __restrict__ mem, unsigned short* __restrict__ mhi,
    unsigned short* __restrict__ mlo)
{
    const int gid = blockIdx.x * 256 + threadIdx.x;  // (b,c,dt,lane)
    const int lane = gid & 63;
    const int dt   = (gid >> 6) & 15;
    const int c    = (gid >> 10) & 63;
    const int b    = gid >> 16;
    const int quad = lane >> 4, n = lane & 15;
    const int s = c * 32 + quad * 8;
    const int d = dt * 16 + n;
    const float* srcp = mem + ((size_t)b * SS + s) * DD + d;
    short8 hi, lo;
#pragma unroll
    for (int j = 0; j < 8; j++) {
        float f = srcp[(size_t)j * DD];
        unsigned short h = f2bf_rne(f);
        hi[j] = (short)h;
        lo[j] = (short)f2bf_rne(f - bf2f(h));
    }
    *(short8*)(mhi + (size_t)gid * 8) = hi;
    *(short8*)(mlo + (size_t)gid * 8) = lo;
}

// ---------------------------------------------------------------------------
// K6: c[b,t,:] = sum_s align_vectors[b,t,s] * mem[b,s,:]  via split-bf16 MFMA.
// READ-ONLY on alignb (already normalized by knorm) — no races.
// ---------------------------------------------------------------------------
__global__ __launch_bounds__(256) void k6_context(
    const float* __restrict__ alignb, const unsigned short* __restrict__ mhi,
    const unsigned short* __restrict__ mlo, float* __restrict__ cbuf)
{
    const int b  = blockIdx.x;
    const int t0 = blockIdx.y * 32;
    const int tid  = threadIdx.x;
    const int wave = tid >> 6, lane = tid & 63;
    const int h  = wave & 1;      // t-half (16 rows)
    const int dh = wave >> 1;     // d-half (128 cols)
    const int quad = lane >> 4, m = lane & 15;

    const int rowl = h * 16 + m;                 // local t row 0..31
    const float* prow = alignb + ((size_t)(b * TT + t0 + rowl)) * SS + quad * 8;

    floatx4 acc[8];
#pragma unroll
    for (int i = 0; i < 8; i++) acc[i] = (floatx4)0.f;

    for (int c = 0; c < 64; c++) {               // s-chunks of 32
        float4 v0 = *(const float4*)(prow + c * 32);
        float4 v1 = *(const float4*)(prow + c * 32 + 4);
        float pv[8] = {v0.x, v0.y, v0.z, v0.w, v1.x, v1.y, v1.z, v1.w};
        short8 a_hi, a_lo;
#pragma unroll
        for (int j = 0; j < 8; j++) {
            unsigned short hh = f2bf_rne(pv[j]);
            a_hi[j] = (short)hh;
            a_lo[j] = (short)f2bf_rne(pv[j] - bf2f(hh));
        }
        const size_t fbase = (((size_t)(b * 64 + c) * 16 + dh * 8) * 64 + lane) * 8;
        const unsigned short* bh = mhi + fbase;
        const unsigned short* bl = mlo + fbase;
#pragma unroll
        for (int dt = 0; dt < 8; dt++) {
            short8 Bh = *(const short8*)(bh + dt * 512);
            short8 Bl = *(const short8*)(bl + dt * 512);
            acc[dt] = __builtin_amdgcn_mfma_f32_16x16x32_bf16(a_hi, Bh, acc[dt], 0, 0, 0);
            acc[dt] = __builtin_amdgcn_mfma_f32_16x16x32_bf16(a_lo, Bh, acc[dt], 0, 0, 0);
            acc[dt] = __builtin_amdgcn_mfma_f32_16x16x32_bf16(a_hi, Bl, acc[dt], 0, 0, 0);
        }
    }

    // C/D layout: col = lane&15 (d), row = quad*4 + reg (t)
#pragma unroll
    for (int dt = 0; dt < 8; dt++) {
        const int d = dh * 128 + dt * 16 + m;
#pragma unroll
        for (int reg = 0; reg < 4; reg++) {
            const int t = t0 + h * 16 + quad * 4 + reg;
            cbuf[((size_t)(b * TT + t)) * DD + d] = acc[dt][reg];
        }
    }
}

// ---------------------------------------------------------------------------
// K7: attn_h = tanh([c, source] @ W_out), W_out is [2D][D] row-major.
// ---------------------------------------------------------------------------
__global__ __launch_bounds__(256) void k7_out(
    const float* __restrict__ cbuf, const float* __restrict__ src,
    const float* __restrict__ W, float* __restrict__ attn)
{
    const int b = blockIdx.y;
    const int t0 = blockIdx.x * 32;
    const int tid = threadIdx.x;
    const int tx = tid & 63, ty = tid >> 6;

    __shared__ __align__(16) float wT[32][256];
    __shared__ float xT[32][32];

    float4 acc[8];
#pragma unroll
    for (int i = 0; i < 8; i++) acc[i] = make_float4(0.f, 0.f, 0.f, 0.f);

    for (int k0 = 0; k0 < 2 * DD; k0 += 32) {
        __syncthreads();
#pragma unroll
        for (int it = 0; it < 8; it++) {
            int f = tid + it * 256;
            int kr = f >> 6, col = (f & 63) * 4;
            *(float4*)&wT[kr][col] =
                *(const float4*)(W + (size_t)(k0 + kr) * DD + col);
        }
#pragma unroll
        for (int rep = 0; rep < 4; rep++) {
            int idx = tid + rep * 256;
            int r = idx >> 5, c = idx & 31;
            int k = k0 + c;
            float x = (k < DD)
                ? cbuf[((size_t)b * TT + t0 + r) * DD + k]
                : src[((size_t)b * TT + t0 + r) * DD + (k - DD)];
            xT[r][c] = x;
        }
        __syncthreads();
#pragma unroll
        for (int kk = 0; kk < 32; kk++) {
            float4 w4 = *(const float4*)&wT[kk][tx * 4];
#pragma unroll
            for (int r4 = 0; r4 < 8; r4++) {
                float x = xT[ty + r4 * 4][kk];
                acc[r4].x += x * w4.x; acc[r4].y += x * w4.y;
                acc[r4].z += x * w4.z; acc[r4].w += x * w4.w;
            }
        }
    }
#pragma unroll
    for (int r4 = 0; r4 < 8; r4++) {
        const int t = t0 + ty + r4 * 4;
        float4 o;
        o.x = tanhf(acc[r4].x); o.y = tanhf(acc[r4].y);
        o.z = tanhf(acc[r4].z); o.w = tanhf(acc[r4].w);
        *(float4*)(attn + ((size_t)b * TT + t) * DD + tx * 4) = o;
    }
}

// ---------------------------------------------------------------------------
extern "C" void kernel_launch(void* const* d_in, const int* in_sizes, int n_in,
                              void* d_out, int out_size, void* d_ws, size_t ws_size,
                              hipStream_t stream)
{
    const float* src  = (const float*)d_in[0];   // [B,T,D]
    const float* mem  = (const float*)d_in[1];   // [B,S,D]
    const float* Wout = (const float*)d_in[2];   // [2D,D]
    const int*   lens = (const int*)d_in[3];     // [B]

    float* out    = (float*)d_out;
    float* attn   = out;                               // [B,T,D]
    float* alignb = out + (size_t)BN * TT * DD;        // [B,T,S] (scratch->final)

    float* rowmax  = (float*)d_ws;                     // B*T
    float* partial = rowmax + (size_t)BN * TT;         // B*T*8
    float* segsum  = partial + (size_t)BN * TT * 8;    // B*NSEG*S
    float* cbuf    = segsum + (size_t)BN * NSEG * SS;  // B*T*D
    unsigned short* mhi = (unsigned short*)(cbuf + (size_t)BN * TT * DD);  // B*S*D bf16 (k6 frag)
    unsigned short* mlo   = mhi + (size_t)BN * SS * DD;                    // B*S*D bf16 (k6 frag)
    unsigned short* shi   = mlo + (size_t)BN * SS * DD;                    // B*T*D bf16 row-major
    unsigned short* slo   = shi + (size_t)BN * TT * DD;
    unsigned short* mhirm = slo + (size_t)BN * TT * DD;                    // B*S*D bf16 row-major
    unsigned short* mlorm = mhirm + (size_t)BN * SS * DD;

    kpre<<<dim3(BN * TT * DD / (256 * 8), 2), 256, 0, stream>>>(
        src, mem, shi, slo, mhirm, mlorm);
    k6pre<<<dim3(BN * 64 * 16 * 64 / 256), 256, 0, stream>>>(mem, mhi, mlo);
    k1_mfma<<<dim3(SS / 128, TT / 128, BN), 256, 0, stream>>>(
        shi, slo, mhirm, mlorm, alignb);
    k2_rowmax<<<dim3(BN * TT), 256, 0, stream>>>(alignb, lens, rowmax);
    k3_segsum<<<dim3(SS / 256, NSEG, BN), 256, 0, stream>>>(alignb, rowmax, lens, segsum);
    k4_prefix<<<dim3(SS / 256, BN), 256, 0, stream>>>(segsum);
    k5_scan<<<dim3(SS / 256, NSEG, BN), 256, 0, stream>>>(alignb, rowmax, segsum, lens, partial);
    knorm<<<dim3(BN * TT), 256, 0, stream>>>(alignb, partial);
    k6_context<<<dim3(BN, TT / 32), 256, 0, stream>>>(alignb, mhi, mlo, cbuf);
    k7_out<<<dim3(TT / 32, BN), 256, 0, stream>>>(cbuf, src, Wout, attn);
}

// Round 5
// 558.301 us; speedup vs baseline: 1.4440x; 1.2218x over previous
//
#include <hip/hip_runtime.h>
#include <math.h>

// Problem constants (B,T,S,D fixed by the reference).
#define BN 8
#define TT 2048
#define SS 2048
#define DD 256
#define NSEG 64
#define SEGLEN 32   // TT / NSEG

typedef __attribute__((ext_vector_type(8))) short short8;
typedef __attribute__((ext_vector_type(4))) float floatx4;

__device__ __forceinline__ unsigned short f2bf_rne(float f) {
    unsigned int u = __float_as_uint(f);
    u = (u + 0x7FFFu + ((u >> 16) & 1u)) >> 16;
    return (unsigned short)u;
}
__device__ __forceinline__ float bf2f(unsigned short h) {
    return __uint_as_float(((unsigned int)h) << 16);
}

// ---------------------------------------------------------------------------
// KPRE: fp32 -> bf16 hi/lo split, row-major, for source (y=0) and memory_bank
// (y=1).  Feeds k1's triple-split MFMA (logits need the precision).
// ---------------------------------------------------------------------------
__global__ __launch_bounds__(256) void kpre(
    const float* __restrict__ src, const float* __restrict__ mem,
    unsigned short* __restrict__ shi, unsigned short* __restrict__ slo,
    unsigned short* __restrict__ mhirm, unsigned short* __restrict__ mlorm)
{
    const float* in; unsigned short *oh, *ol;
    if (blockIdx.y == 0) { in = src; oh = shi; ol = slo; }
    else                 { in = mem; oh = mhirm; ol = mlorm; }
    const size_t base = ((size_t)blockIdx.x * 256 + threadIdx.x) * 8;
    float4 v0 = *(const float4*)(in + base);
    float4 v1 = *(const float4*)(in + base + 4);
    float f[8] = {v0.x, v0.y, v0.z, v0.w, v1.x, v1.y, v1.z, v1.w};
    short8 hv, lv;
#pragma unroll
    for (int j = 0; j < 8; j++) {
        unsigned short h = f2bf_rne(f[j]);
        hv[j] = (short)h;
        lv[j] = (short)f2bf_rne(f[j] - bf2f(h));
    }
    *(short8*)(oh + base) = hv;
    *(short8*)(ol + base) = lv;
}

// ---------------------------------------------------------------------------
// K1: align[b,t,s] = dot(src, mem) via split-bf16 MFMA (3-term), fp32 acc.
// 128x128 tile; 4 waves 2x2, each 64t x 64s.  No LDS/barriers.  Blocks whose
// whole s-range is masked (s0 >= len) exit: garbage there is overwritten by
// k5 and masked in k2/k3.
// ---------------------------------------------------------------------------
__global__ __launch_bounds__(256) void k1_mfma(
    const unsigned short* __restrict__ shi, const unsigned short* __restrict__ slo,
    const unsigned short* __restrict__ mhirm, const unsigned short* __restrict__ mlorm,
    const int* __restrict__ lens, float* __restrict__ alignb)
{
    const int b  = blockIdx.z;
    const int s0 = blockIdx.x * 128;
    if (s0 >= lens[b]) return;
    const int t0 = blockIdx.y * 128;
    const int tid = threadIdx.x;
    const int wave = tid >> 6, lane = tid & 63;
    const int wt = wave & 1, wsb = wave >> 1;
    const int quad = lane >> 4, r = lane & 15;

    const size_t aRow = ((size_t)(b * TT + t0 + wt * 64 + r)) * DD + quad * 8;
    const size_t bRow = ((size_t)(b * SS + s0 + wsb * 64 + r)) * DD + quad * 8;
    const unsigned short* pAh = shi + aRow;
    const unsigned short* pAl = slo + aRow;
    const unsigned short* pBh = mhirm + bRow;
    const unsigned short* pBl = mlorm + bRow;

    floatx4 acc[4][4];
#pragma unroll
    for (int i = 0; i < 4; i++)
#pragma unroll
        for (int j = 0; j < 4; j++) acc[i][j] = (floatx4)0.f;

    for (int kc = 0; kc < 8; kc++) {
        const int ko = kc * 32;
        short8 Ah[4], Al[4], Bh[4], Bl[4];
#pragma unroll
        for (int f = 0; f < 4; f++) {
            Ah[f] = *(const short8*)(pAh + (size_t)(f * 16) * DD + ko);
            Al[f] = *(const short8*)(pAl + (size_t)(f * 16) * DD + ko);
            Bh[f] = *(const short8*)(pBh + (size_t)(f * 16) * DD + ko);
            Bl[f] = *(const short8*)(pBl + (size_t)(f * 16) * DD + ko);
        }
#pragma unroll
        for (int mf = 0; mf < 4; mf++)
#pragma unroll
            for (int nf = 0; nf < 4; nf++) {
                acc[mf][nf] = __builtin_amdgcn_mfma_f32_16x16x32_bf16(
                    Ah[mf], Bh[nf], acc[mf][nf], 0, 0, 0);
                acc[mf][nf] = __builtin_amdgcn_mfma_f32_16x16x32_bf16(
                    Al[mf], Bh[nf], acc[mf][nf], 0, 0, 0);
                acc[mf][nf] = __builtin_amdgcn_mfma_f32_16x16x32_bf16(
                    Ah[mf], Bl[nf], acc[mf][nf], 0, 0, 0);
            }
    }

#pragma unroll
    for (int mf = 0; mf < 4; mf++)
#pragma unroll
        for (int reg = 0; reg < 4; reg++) {
            const int t = t0 + wt * 64 + mf * 16 + quad * 4 + reg;
            float* row = alignb + ((size_t)(b * TT + t)) * SS + s0 + wsb * 64 + r;
#pragma unroll
            for (int nf = 0; nf < 4; nf++)
                row[nf * 16] = acc[mf][nf][reg];
        }
}

// ---------------------------------------------------------------------------
// K2: rowmax over valid s.
// ---------------------------------------------------------------------------
__global__ __launch_bounds__(256) void k2_rowmax(
    const float* __restrict__ alignb, const int* __restrict__ lens,
    float* __restrict__ rowmax)
{
    const int row = blockIdx.x;        // b*TT + t
    const int b = row >> 11;
    const int len = lens[b];
    const float* r = alignb + (size_t)row * SS;
    float m = -INFINITY;
    for (int s = threadIdx.x; s < len; s += 256) m = fmaxf(m, r[s]);
#pragma unroll
    for (int off = 32; off > 0; off >>= 1) m = fmaxf(m, __shfl_down(m, off, 64));
    __shared__ float w[4];
    if ((threadIdx.x & 63) == 0) w[threadIdx.x >> 6] = m;
    __syncthreads();
    if (threadIdx.x == 0)
        rowmax[row] = fmaxf(fmaxf(w[0], w[1]), fmaxf(w[2], w[3]));
}

// ---------------------------------------------------------------------------
// K3: per-(b,seg,s) sum over the segment's 32 rows of e = exp(align - max).
// Threads with s >= len write 0 and exit (no loads).
// ---------------------------------------------------------------------------
__global__ __launch_bounds__(256) void k3_segsum(
    const float* __restrict__ alignb, const float* __restrict__ rowmax,
    const int* __restrict__ lens, float* __restrict__ segsum)
{
    const int b = blockIdx.z, seg = blockIdx.y;
    const int s = blockIdx.x * 256 + threadIdx.x;
    const size_t oidx = ((size_t)b * NSEG + seg) * SS + s;
    if (s >= lens[b]) { segsum[oidx] = 0.f; return; }
    const float* base = alignb + ((size_t)b * TT + seg * SEGLEN) * SS + s;
    const float* rm = rowmax + b * TT + seg * SEGLEN;
    float sum = 0.f;
#pragma unroll 4
    for (int r = 0; r < SEGLEN; r++)
        sum += expf(base[(size_t)r * SS] - rm[r]);
    segsum[oidx] = sum;
}

// ---------------------------------------------------------------------------
// K4: exclusive prefix over the 64 segments, per (b,s) column, in place.
// Batched preloads (8 at a time) to overlap latency.
// ---------------------------------------------------------------------------
__global__ __launch_bounds__(256) void k4_prefix(float* __restrict__ segsum)
{
    const int b = blockIdx.y;
    const int s = blockIdx.x * 256 + threadIdx.x;
    float run = 0.f;
    for (int g = 0; g < NSEG / 8; g++) {
        float v[8];
#pragma unroll
        for (int i = 0; i < 8; i++)
            v[i] = segsum[((size_t)b * NSEG + g * 8 + i) * SS + s];
#pragma unroll
        for (int i = 0; i < 8; i++) {
            segsum[((size_t)b * NSEG + g * 8 + i) * SS + s] = run;
            run += v[i];
        }
    }
}

// ---------------------------------------------------------------------------
// K5: full-row scan + normalize.  Block = (seg, b): 32 t-rows x all 2048 s.
// Each thread owns 8 contiguous cols (2 float4).  At each row the full row
// sum is block-reduced, so the FINAL normalized align_vectors is written
// directly (fp32, in place) — knorm is gone.  Cols >= len write exact 0.
// ---------------------------------------------------------------------------
__global__ __launch_bounds__(256) void k5_scan(
    float* __restrict__ alignb, const float* __restrict__ rowmax,
    const float* __restrict__ segsum, const int* __restrict__ lens,
    float* __restrict__ dummy)
{
    const int seg = blockIdx.x, b = blockIdx.y;
    const int len = lens[b];
    const int c0 = threadIdx.x * 8;          // first of 8 contiguous cols
    const int lane = threadIdx.x & 63, wid = threadIdx.x >> 6;

    float psum[8];
    {
        const float* sp = segsum + ((size_t)b * NSEG + seg) * SS + c0;
        float4 a = *(const float4*)sp, c = *(const float4*)(sp + 4);
        psum[0] = a.x; psum[1] = a.y; psum[2] = a.z; psum[3] = a.w;
        psum[4] = c.x; psum[5] = c.y; psum[6] = c.z; psum[7] = c.w;
    }

    __shared__ float red[8];                 // ping-pong 2 x 4 waves

    for (int r = 0; r < SEGLEN; r++) {
        const int t = seg * SEGLEN + r;
        const float m = rowmax[b * TT + t];
        float* rowp = alignb + ((size_t)(b * TT + t)) * SS + c0;
        float u[8];
        float rsum = 0.f;
        if (c0 + 8 <= len) {                 // fully valid (common case)
            float4 a = *(const float4*)rowp, c = *(const float4*)(rowp + 4);
            float av[8] = {a.x, a.y, a.z, a.w, c.x, c.y, c.z, c.w};
#pragma unroll
            for (int j = 0; j < 8; j++) {
                float e = expf(av[j] - m);
                float div = (t == 0) ? 1.0f : (psum[j] + 1e-20f);
                u[j] = e / div;
                psum[j] += e;
                rsum += u[j];
            }
        } else {
#pragma unroll
            for (int j = 0; j < 8; j++) {
                float e = (c0 + j < len) ? expf(rowp[j] - m) : 0.f;
                float div = (t == 0) ? 1.0f : (psum[j] + 1e-20f);
                u[j] = e / div;
                psum[j] += e;
                rsum += u[j];
            }
        }
        // block-reduce rsum (ping-pong LDS, one barrier per row)
#pragma unroll
        for (int off = 32; off > 0; off >>= 1)
            rsum += __shfl_down(rsum, off, 64);
        const int pp = (r & 1) * 4;
        if (lane == 0) red[pp + wid] = rsum;
        __syncthreads();
        const float inv = 1.0f / (red[pp] + red[pp + 1] + red[pp + 2] + red[pp + 3]);
        float4 o0 = {u[0] * inv, u[1] * inv, u[2] * inv, u[3] * inv};
        float4 o1 = {u[4] * inv, u[5] * inv, u[6] * inv, u[7] * inv};
        *(float4*)rowp = o0;
        *(float4*)(rowp + 4) = o1;
    }
    (void)dummy;
}

// ---------------------------------------------------------------------------
// K6pre: memory_bank -> MFMA B-fragment layout, single bf16 (RNE).
// frag[(((b*64 + c)*16 + dt)*64 + lane)*8 + j], lane holds B[k=quad*8+j][n=lane&15].
// ---------------------------------------------------------------------------
__global__ __launch_bounds__(256) void k6pre(
    const float* __restrict__ mem, unsigned short* __restrict__ mhi)
{
    const int gid = blockIdx.x * 256 + threadIdx.x;
    const int lane = gid & 63;
    const int dt   = (gid >> 6) & 15;
    const int c    = (gid >> 10) & 63;
    const int b    = gid >> 16;
    const int quad = lane >> 4, n = lane & 15;
    const int s = c * 32 + quad * 8;
    const int d = dt * 16 + n;
    const float* srcp = mem + ((size_t)b * SS + s) * DD + d;
    short8 hi;
#pragma unroll
    for (int j = 0; j < 8; j++)
        hi[j] = (short)f2bf_rne(srcp[(size_t)j * DD]);
    *(short8*)(mhi + (size_t)gid * 8) = hi;
}

// ---------------------------------------------------------------------------
// K6: cpart[sq] += p @ mem over s-range [sq*512, sq*512+512), single-bf16
// MFMA.  Grid (b, t-tile of 64, sq of 4) = 1024 blocks; 4 waves each own a
// 64-wide d-slice, all 64 t.  A packed from normalized fp32 p via RTZ
// (shift/or — 3 int-ops per pair).  s-chunks >= len skipped (p is 0 there).
// ---------------------------------------------------------------------------
__global__ __launch_bounds__(256, 4) void k6_context(
    const float* __restrict__ alignb, const unsigned short* __restrict__ mhi,
    const int* __restrict__ lens, float* __restrict__ cpart)
{
    const int b  = blockIdx.x;
    const int t0 = blockIdx.y * 64;
    const int sq = blockIdx.z;
    const int tid  = threadIdx.x;
    const int wave = tid >> 6, lane = tid & 63;
    const int quad = lane >> 4, m = lane & 15;

    const int len = lens[b];
    int cmax = (len - sq * 512 + 31) >> 5;
    cmax = cmax < 0 ? 0 : (cmax > 16 ? 16 : cmax);

    floatx4 acc[4][4];                       // [mf][dt]
#pragma unroll
    for (int i = 0; i < 4; i++)
#pragma unroll
        for (int j = 0; j < 4; j++) acc[i][j] = (floatx4)0.f;

    const float* aBase = alignb + ((size_t)(b * TT + t0 + m)) * SS + sq * 512 + quad * 8;

    for (int c = 0; c < cmax; c++) {
        const int cg = sq * 16 + c;
        short8 Bf[4];
#pragma unroll
        for (int j = 0; j < 4; j++) {
            const int dt = wave * 4 + j;
            Bf[j] = *(const short8*)(mhi +
                (((size_t)(b * 64 + cg) * 16 + dt) * 64 + lane) * 8);
        }
#pragma unroll
        for (int mf = 0; mf < 4; mf++) {
            const float* ap = aBase + (size_t)(mf * 16) * SS + c * 32;
            float4 v0 = *(const float4*)ap;
            float4 v1 = *(const float4*)(ap + 4);
            union { short8 s; unsigned int u[4]; } pk;   // bf16 RTZ pack
            pk.u[0] = (__float_as_uint(v0.x) >> 16) | (__float_as_uint(v0.y) & 0xFFFF0000u);
            pk.u[1] = (__float_as_uint(v0.z) >> 16) | (__float_as_uint(v0.w) & 0xFFFF0000u);
            pk.u[2] = (__float_as_uint(v1.x) >> 16) | (__float_as_uint(v1.y) & 0xFFFF0000u);
            pk.u[3] = (__float_as_uint(v1.z) >> 16) | (__float_as_uint(v1.w) & 0xFFFF0000u);
#pragma unroll
            for (int j = 0; j < 4; j++)
                acc[mf][j] = __builtin_amdgcn_mfma_f32_16x16x32_bf16(
                    pk.s, Bf[j], acc[mf][j], 0, 0, 0);
        }
    }

    // C/D layout: col = lane&15 (d), row = quad*4 + reg (t)
    float* out = cpart + (size_t)sq * BN * TT * DD;
#pragma unroll
    for (int mf = 0; mf < 4; mf++)
#pragma unroll
        for (int j = 0; j < 4; j++) {
            const int d = wave * 64 + j * 16 + m;
#pragma unroll
            for (int reg = 0; reg < 4; reg++) {
                const int t = t0 + mf * 16 + quad * 4 + reg;
                out[((size_t)(b * TT + t)) * DD + d] = acc[mf][j][reg];
            }
        }
}

// ---------------------------------------------------------------------------
// K7: attn_h = tanh([c, source] @ W_out); c summed from the 4 k6 partials
// during staging.
// ---------------------------------------------------------------------------
__global__ __launch_bounds__(256) void k7_out(
    const float* __restrict__ cpart, const float* __restrict__ src,
    const float* __restrict__ W, float* __restrict__ attn)
{
    const int b = blockIdx.y;
    const int t0 = blockIdx.x * 32;
    const int tid = threadIdx.x;
    const int tx = tid & 63, ty = tid >> 6;
    const size_t PSTRIDE = (size_t)BN * TT * DD;

    __shared__ __align__(16) float wT[32][256];
    __shared__ float xT[32][32];

    float4 acc[8];
#pragma unroll
    for (int i = 0; i < 8; i++) acc[i] = make_float4(0.f, 0.f, 0.f, 0.f);

    for (int k0 = 0; k0 < 2 * DD; k0 += 32) {
        __syncthreads();
#pragma unroll
        for (int it = 0; it < 8; it++) {
            int f = tid + it * 256;
            int kr = f >> 6, col = (f & 63) * 4;
            *(float4*)&wT[kr][col] =
                *(const float4*)(W + (size_t)(k0 + kr) * DD + col);
        }
#pragma unroll
        for (int rep = 0; rep < 4; rep++) {
            int idx = tid + rep * 256;
            int r = idx >> 5, c = idx & 31;
            int k = k0 + c;
            float x;
            if (k < DD) {
                const size_t ci = ((size_t)b * TT + t0 + r) * DD + k;
                x = cpart[ci] + cpart[ci + PSTRIDE] +
                    cpart[ci + 2 * PSTRIDE] + cpart[ci + 3 * PSTRIDE];
            } else {
                x = src[((size_t)b * TT + t0 + r) * DD + (k - DD)];
            }
            xT[r][c] = x;
        }
        __syncthreads();
#pragma unroll
        for (int kk = 0; kk < 32; kk++) {
            float4 w4 = *(const float4*)&wT[kk][tx * 4];
#pragma unroll
            for (int r4 = 0; r4 < 8; r4++) {
                float x = xT[ty + r4 * 4][kk];
                acc[r4].x += x * w4.x; acc[r4].y += x * w4.y;
                acc[r4].z += x * w4.z; acc[r4].w += x * w4.w;
            }
        }
    }
#pragma unroll
    for (int r4 = 0; r4 < 8; r4++) {
        const int t = t0 + ty + r4 * 4;
        float4 o;
        o.x = tanhf(acc[r4].x); o.y = tanhf(acc[r4].y);
        o.z = tanhf(acc[r4].z); o.w = tanhf(acc[r4].w);
        *(float4*)(attn + ((size_t)b * TT + t) * DD + tx * 4) = o;
    }
}

// ---------------------------------------------------------------------------
extern "C" void kernel_launch(void* const* d_in, const int* in_sizes, int n_in,
                              void* d_out, int out_size, void* d_ws, size_t ws_size,
                              hipStream_t stream)
{
    const float* src  = (const float*)d_in[0];   // [B,T,D]
    const float* mem  = (const float*)d_in[1];   // [B,S,D]
    const float* Wout = (const float*)d_in[2];   // [2D,D]
    const int*   lens = (const int*)d_in[3];     // [B]

    float* out    = (float*)d_out;
    float* attn   = out;                               // [B,T,D]
    float* alignb = out + (size_t)BN * TT * DD;        // [B,T,S] scratch -> final

    // ws layout (with aliasing; ~76 MB total):
    float* rowmax = (float*)d_ws;                                  // 64 KB
    float* segsum = rowmax + (size_t)BN * TT;                      // 4 MB
    unsigned short* mhi = (unsigned short*)(segsum + (size_t)BN * NSEG * SS); // 8 MB
    unsigned short* shi   = mhi + (size_t)BN * SS * DD;            // 8 MB (dead after k1)
    unsigned short* slo   = shi + (size_t)BN * TT * DD;            // 8 MB (dead after k1)
    unsigned short* mhirm = slo + (size_t)BN * TT * DD;            // 8 MB (dead after k1)
    unsigned short* mlorm = mhirm + (size_t)BN * SS * DD;          // 8 MB (dead after k1)
    // cpart (64 MB) aliases the 32 MB of k1-only bf16 buffers + 32 MB fresh.
    float* cpart = (float*)shi;

    kpre<<<dim3(BN * TT * DD / (256 * 8), 2), 256, 0, stream>>>(
        src, mem, shi, slo, mhirm, mlorm);
    k6pre<<<dim3(BN * 64 * 16 * 64 / 256), 256, 0, stream>>>(mem, mhi);
    k1_mfma<<<dim3(SS / 128, TT / 128, BN), 256, 0, stream>>>(
        shi, slo, mhirm, mlorm, lens, alignb);
    k2_rowmax<<<dim3(BN * TT), 256, 0, stream>>>(alignb, lens, rowmax);
    k3_segsum<<<dim3(SS / 256, NSEG, BN), 256, 0, stream>>>(alignb, rowmax, lens, segsum);
    k4_prefix<<<dim3(SS / 256, BN), 256, 0, stream>>>(segsum);
    k5_scan<<<dim3(NSEG, BN), 256, 0, stream>>>(alignb, rowmax, segsum, lens, nullptr);
    k6_context<<<dim3(BN, TT / 64, 4), 256, 0, stream>>>(alignb, mhi, lens, cpart);
    k7_out<<<dim3(TT / 32, BN), 256, 0, stream>>>(cpart, src, Wout, attn);
}

// Round 6
// 488.892 us; speedup vs baseline: 1.6491x; 1.1420x over previous
//
#include <hip/hip_runtime.h>
#include <math.h>

// Problem constants (B,T,S,D fixed by the reference).
#define BN 8
#define TT 2048
#define SS 2048
#define DD 256
#define NSEG 64
#define SEGLEN 32   // TT / NSEG

typedef __attribute__((ext_vector_type(8))) short short8;
typedef __attribute__((ext_vector_type(4))) float floatx4;

__device__ __forceinline__ unsigned short f2bf_rne(float f) {
    unsigned int u = __float_as_uint(f);
    u = (u + 0x7FFFu + ((u >> 16) & 1u)) >> 16;
    return (unsigned short)u;
}
__device__ __forceinline__ float bf2f(unsigned short h) {
    return __uint_as_float(((unsigned int)h) << 16);
}

// Async global->LDS DMA, 16 B per lane.  LDS dest must be wave-uniform base
// + lane*16 (m104/m108) — all call sites below satisfy this.
__device__ __forceinline__ void async16(const unsigned short* g, unsigned short* l) {
    __builtin_amdgcn_global_load_lds(
        (const __attribute__((address_space(1))) unsigned int*)g,
        (__attribute__((address_space(3))) unsigned int*)l,
        16, 0, 0);
}

// ---------------------------------------------------------------------------
// KPRE: fp32 -> bf16 hi/lo split, row-major, for source (y=0) and memory_bank
// (y=1).  Feeds k1's triple-split MFMA (logits need the precision).
// ---------------------------------------------------------------------------
__global__ __launch_bounds__(256) void kpre(
    const float* __restrict__ src, const float* __restrict__ mem,
    unsigned short* __restrict__ shi, unsigned short* __restrict__ slo,
    unsigned short* __restrict__ mhirm, unsigned short* __restrict__ mlorm)
{
    const float* in; unsigned short *oh, *ol;
    if (blockIdx.y == 0) { in = src; oh = shi; ol = slo; }
    else                 { in = mem; oh = mhirm; ol = mlorm; }
    const size_t base = ((size_t)blockIdx.x * 256 + threadIdx.x) * 8;
    float4 v0 = *(const float4*)(in + base);
    float4 v1 = *(const float4*)(in + base + 4);
    float f[8] = {v0.x, v0.y, v0.z, v0.w, v1.x, v1.y, v1.z, v1.w};
    short8 hv, lv;
#pragma unroll
    for (int j = 0; j < 8; j++) {
        unsigned short h = f2bf_rne(f[j]);
        hv[j] = (short)h;
        lv[j] = (short)f2bf_rne(f[j] - bf2f(h));
    }
    *(short8*)(oh + base) = hv;
    *(short8*)(ol + base) = lv;
}

// ---------------------------------------------------------------------------
// K1: align = src @ mem^T via split-bf16 MFMA (3-term), fp32 acc.
// m97-style structure: 128x128 tile, BK=32, 4 sub-tiles (Ah/Al/Bh/Bl, 8 KB
// each) staged to LDS via global_load_lds width=16, 2-barrier K-loop,
// fragments via ds_read_b128.  4 waves 2x2, each 64t x 64s.
// Blocks with s0 >= len exit (k5 overwrites / k2-k3 mask that region).
// ---------------------------------------------------------------------------
__global__ __launch_bounds__(256) void k1_mfma(
    const unsigned short* __restrict__ shi, const unsigned short* __restrict__ slo,
    const unsigned short* __restrict__ mhirm, const unsigned short* __restrict__ mlorm,
    const int* __restrict__ lens, float* __restrict__ alignb)
{
    const int b  = blockIdx.z;
    const int s0 = blockIdx.x * 128;
    if (s0 >= lens[b]) return;
    const int t0 = blockIdx.y * 128;
    const int tid = threadIdx.x;
    const int wave = tid >> 6, lane = tid & 63;
    const int wt = wave & 1, wsb = wave >> 1;
    const int quad = lane >> 4, m = lane & 15;

    // 4 x [128 rows][32 k] bf16 sub-tiles, 8 KB each.
    __shared__ unsigned short ldsAh[128 * 32];
    __shared__ unsigned short ldsAl[128 * 32];
    __shared__ unsigned short ldsBh[128 * 32];
    __shared__ unsigned short ldsBl[128 * 32];

    // Staging addresses: chunk c = tid + i*256 (i=0,1); row = c>>2, k4 = c&3.
    const int srow = tid >> 2, sk4 = (tid & 3) * 8;
    const size_t aBase = ((size_t)(b * TT + t0 + srow)) * DD + sk4;
    const size_t bBase = ((size_t)(b * SS + s0 + srow)) * DD + sk4;
    // second chunk: c += 256 -> row += 64
    const size_t aBase2 = aBase + (size_t)64 * DD;
    const size_t bBase2 = bBase + (size_t)64 * DD;
    unsigned short* l1 = nullptr;  // per-thread LDS chunk offsets
    const int lo1 = tid * 8, lo2 = tid * 8 + 2048;

    floatx4 acc[4][4];
#pragma unroll
    for (int i = 0; i < 4; i++)
#pragma unroll
        for (int j = 0; j < 4; j++) acc[i][j] = (floatx4)0.f;

    for (int kc = 0; kc < 8; kc++) {
        const int ko = kc * 32;
        __syncthreads();                 // previous iteration's reads done
        async16(shi   + aBase  + ko, ldsAh + lo1);
        async16(shi   + aBase2 + ko, ldsAh + lo2);
        async16(slo   + aBase  + ko, ldsAl + lo1);
        async16(slo   + aBase2 + ko, ldsAl + lo2);
        async16(mhirm + bBase  + ko, ldsBh + lo1);
        async16(mhirm + bBase2 + ko, ldsBh + lo2);
        async16(mlorm + bBase  + ko, ldsBl + lo1);
        async16(mlorm + bBase2 + ko, ldsBl + lo2);
        __syncthreads();                 // drains vmcnt(0) then barrier

        short8 Ah[4], Al[4], Bh[4], Bl[4];
#pragma unroll
        for (int f = 0; f < 4; f++) {
            const int ra = (wt * 64 + f * 16 + m) * 32 + quad * 8;
            const int rb = (wsb * 64 + f * 16 + m) * 32 + quad * 8;
            Ah[f] = *(const short8*)&ldsAh[ra];
            Al[f] = *(const short8*)&ldsAl[ra];
            Bh[f] = *(const short8*)&ldsBh[rb];
            Bl[f] = *(const short8*)&ldsBl[rb];
        }
#pragma unroll
        for (int mf = 0; mf < 4; mf++)
#pragma unroll
            for (int nf = 0; nf < 4; nf++) {
                acc[mf][nf] = __builtin_amdgcn_mfma_f32_16x16x32_bf16(
                    Ah[mf], Bh[nf], acc[mf][nf], 0, 0, 0);
                acc[mf][nf] = __builtin_amdgcn_mfma_f32_16x16x32_bf16(
                    Al[mf], Bh[nf], acc[mf][nf], 0, 0, 0);
                acc[mf][nf] = __builtin_amdgcn_mfma_f32_16x16x32_bf16(
                    Ah[mf], Bl[nf], acc[mf][nf], 0, 0, 0);
            }
    }
    (void)l1;

#pragma unroll
    for (int mf = 0; mf < 4; mf++)
#pragma unroll
        for (int reg = 0; reg < 4; reg++) {
            const int t = t0 + wt * 64 + mf * 16 + quad * 4 + reg;
            float* row = alignb + ((size_t)(b * TT + t)) * SS + s0 + wsb * 64 + m;
#pragma unroll
            for (int nf = 0; nf < 4; nf++)
                row[nf * 16] = acc[mf][nf][reg];
        }
}

// ---------------------------------------------------------------------------
// K2: rowmax over valid s.
// ---------------------------------------------------------------------------
__global__ __launch_bounds__(256) void k2_rowmax(
    const float* __restrict__ alignb, const int* __restrict__ lens,
    float* __restrict__ rowmax)
{
    const int row = blockIdx.x;        // b*TT + t
    const int b = row >> 11;
    const int len = lens[b];
    const float* r = alignb + (size_t)row * SS;
    float m = -INFINITY;
    for (int s = threadIdx.x; s < len; s += 256) m = fmaxf(m, r[s]);
#pragma unroll
    for (int off = 32; off > 0; off >>= 1) m = fmaxf(m, __shfl_down(m, off, 64));
    __shared__ float w[4];
    if ((threadIdx.x & 63) == 0) w[threadIdx.x >> 6] = m;
    __syncthreads();
    if (threadIdx.x == 0)
        rowmax[row] = fmaxf(fmaxf(w[0], w[1]), fmaxf(w[2], w[3]));
}

// ---------------------------------------------------------------------------
// K3: per-(b,seg,s) sum over the segment's 32 rows of e = exp(align - max).
// ---------------------------------------------------------------------------
__global__ __launch_bounds__(256) void k3_segsum(
    const float* __restrict__ alignb, const float* __restrict__ rowmax,
    const int* __restrict__ lens, float* __restrict__ segsum)
{
    const int b = blockIdx.z, seg = blockIdx.y;
    const int s = blockIdx.x * 256 + threadIdx.x;
    const size_t oidx = ((size_t)b * NSEG + seg) * SS + s;
    if (s >= lens[b]) { segsum[oidx] = 0.f; return; }
    const float* base = alignb + ((size_t)b * TT + seg * SEGLEN) * SS + s;
    const float* rm = rowmax + b * TT + seg * SEGLEN;
    float sum = 0.f;
#pragma unroll 4
    for (int r = 0; r < SEGLEN; r++)
        sum += expf(base[(size_t)r * SS] - rm[r]);
    segsum[oidx] = sum;
}

// ---------------------------------------------------------------------------
// K4: exclusive prefix over the 64 segments, per (b,s) column, in place.
// ---------------------------------------------------------------------------
__global__ __launch_bounds__(256) void k4_prefix(float* __restrict__ segsum)
{
    const int b = blockIdx.y;
    const int s = blockIdx.x * 256 + threadIdx.x;
    float run = 0.f;
    for (int g = 0; g < NSEG / 8; g++) {
        float v[8];
#pragma unroll
        for (int i = 0; i < 8; i++)
            v[i] = segsum[((size_t)b * NSEG + g * 8 + i) * SS + s];
#pragma unroll
        for (int i = 0; i < 8; i++) {
            segsum[((size_t)b * NSEG + g * 8 + i) * SS + s] = run;
            run += v[i];
        }
    }
}

// ---------------------------------------------------------------------------
// K5: full-row scan + normalize.  Block = (seg, b): 32 t-rows x all 2048 s.
// Writes the FINAL normalized align_vectors in place.  Cols >= len get 0.
// ---------------------------------------------------------------------------
__global__ __launch_bounds__(256) void k5_scan(
    float* __restrict__ alignb, const float* __restrict__ rowmax,
    const float* __restrict__ segsum, const int* __restrict__ lens)
{
    const int seg = blockIdx.x, b = blockIdx.y;
    const int len = lens[b];
    const int c0 = threadIdx.x * 8;
    const int lane = threadIdx.x & 63, wid = threadIdx.x >> 6;

    float psum[8];
    {
        const float* sp = segsum + ((size_t)b * NSEG + seg) * SS + c0;
        float4 a = *(const float4*)sp, c = *(const float4*)(sp + 4);
        psum[0] = a.x; psum[1] = a.y; psum[2] = a.z; psum[3] = a.w;
        psum[4] = c.x; psum[5] = c.y; psum[6] = c.z; psum[7] = c.w;
    }

    __shared__ float red[8];

    for (int r = 0; r < SEGLEN; r++) {
        const int t = seg * SEGLEN + r;
        const float m = rowmax[b * TT + t];
        float* rowp = alignb + ((size_t)(b * TT + t)) * SS + c0;
        float u[8];
        float rsum = 0.f;
        if (c0 + 8 <= len) {
            float4 a = *(const float4*)rowp, c = *(const float4*)(rowp + 4);
            float av[8] = {a.x, a.y, a.z, a.w, c.x, c.y, c.z, c.w};
#pragma unroll
            for (int j = 0; j < 8; j++) {
                float e = expf(av[j] - m);
                float div = (t == 0) ? 1.0f : (psum[j] + 1e-20f);
                u[j] = e / div;
                psum[j] += e;
                rsum += u[j];
            }
        } else {
#pragma unroll
            for (int j = 0; j < 8; j++) {
                float e = (c0 + j < len) ? expf(rowp[j] - m) : 0.f;
                float div = (t == 0) ? 1.0f : (psum[j] + 1e-20f);
                u[j] = e / div;
                psum[j] += e;
                rsum += u[j];
            }
        }
#pragma unroll
        for (int off = 32; off > 0; off >>= 1)
            rsum += __shfl_down(rsum, off, 64);
        const int pp = (r & 1) * 4;
        if (lane == 0) red[pp + wid] = rsum;
        __syncthreads();
        const float inv = 1.0f / (red[pp] + red[pp + 1] + red[pp + 2] + red[pp + 3]);
        float4 o0 = {u[0] * inv, u[1] * inv, u[2] * inv, u[3] * inv};
        float4 o1 = {u[4] * inv, u[5] * inv, u[6] * inv, u[7] * inv};
        *(float4*)rowp = o0;
        *(float4*)(rowp + 4) = o1;
    }
}

// ---------------------------------------------------------------------------
// K6pre: memory_bank -> MFMA B-fragment layout, single bf16 (RNE).
// ---------------------------------------------------------------------------
__global__ __launch_bounds__(256) void k6pre(
    const float* __restrict__ mem, unsigned short* __restrict__ mhi)
{
    const int gid = blockIdx.x * 256 + threadIdx.x;
    const int lane = gid & 63;
    const int dt   = (gid >> 6) & 15;
    const int c    = (gid >> 10) & 63;
    const int b    = gid >> 16;
    const int quad = lane >> 4, n = lane & 15;
    const int s = c * 32 + quad * 8;
    const int d = dt * 16 + n;
    const float* srcp = mem + ((size_t)b * SS + s) * DD + d;
    short8 hi;
#pragma unroll
    for (int j = 0; j < 8; j++)
        hi[j] = (short)f2bf_rne(srcp[(size_t)j * DD]);
    *(short8*)(mhi + (size_t)gid * 8) = hi;
}

// ---------------------------------------------------------------------------
// K6: cpart[sq] = p @ mem over s-range [sq*512, sq*512+512), single-bf16
// MFMA.  Grid (b, t-tile 64, sq 4); 4 waves each own a 64-wide d-slice.
// ---------------------------------------------------------------------------
__global__ __launch_bounds__(256, 4) void k6_context(
    const float* __restrict__ alignb, const unsigned short* __restrict__ mhi,
    const int* __restrict__ lens, float* __restrict__ cpart)
{
    const int b  = blockIdx.x;
    const int t0 = blockIdx.y * 64;
    const int sq = blockIdx.z;
    const int tid  = threadIdx.x;
    const int wave = tid >> 6, lane = tid & 63;
    const int quad = lane >> 4, m = lane & 15;

    const int len = lens[b];
    int cmax = (len - sq * 512 + 31) >> 5;
    cmax = cmax < 0 ? 0 : (cmax > 16 ? 16 : cmax);

    floatx4 acc[4][4];
#pragma unroll
    for (int i = 0; i < 4; i++)
#pragma unroll
        for (int j = 0; j < 4; j++) acc[i][j] = (floatx4)0.f;

    const float* aBase = alignb + ((size_t)(b * TT + t0 + m)) * SS + sq * 512 + quad * 8;

    for (int c = 0; c < cmax; c++) {
        const int cg = sq * 16 + c;
        short8 Bf[4];
#pragma unroll
        for (int j = 0; j < 4; j++) {
            const int dt = wave * 4 + j;
            Bf[j] = *(const short8*)(mhi +
                (((size_t)(b * 64 + cg) * 16 + dt) * 64 + lane) * 8);
        }
#pragma unroll
        for (int mf = 0; mf < 4; mf++) {
            const float* ap = aBase + (size_t)(mf * 16) * SS + c * 32;
            float4 v0 = *(const float4*)ap;
            float4 v1 = *(const float4*)(ap + 4);
            union { short8 s; unsigned int u[4]; } pk;   // bf16 RTZ pack
            pk.u[0] = (__float_as_uint(v0.x) >> 16) | (__float_as_uint(v0.y) & 0xFFFF0000u);
            pk.u[1] = (__float_as_uint(v0.z) >> 16) | (__float_as_uint(v0.w) & 0xFFFF0000u);
            pk.u[2] = (__float_as_uint(v1.x) >> 16) | (__float_as_uint(v1.y) & 0xFFFF0000u);
            pk.u[3] = (__float_as_uint(v1.z) >> 16) | (__float_as_uint(v1.w) & 0xFFFF0000u);
#pragma unroll
            for (int j = 0; j < 4; j++)
                acc[mf][j] = __builtin_amdgcn_mfma_f32_16x16x32_bf16(
                    pk.s, Bf[j], acc[mf][j], 0, 0, 0);
        }
    }

    float* out = cpart + (size_t)sq * BN * TT * DD;
#pragma unroll
    for (int mf = 0; mf < 4; mf++)
#pragma unroll
        for (int j = 0; j < 4; j++) {
            const int d = wave * 64 + j * 16 + m;
#pragma unroll
            for (int reg = 0; reg < 4; reg++) {
                const int t = t0 + mf * 16 + quad * 4 + reg;
                out[((size_t)(b * TT + t)) * DD + d] = acc[mf][j][reg];
            }
        }
}

// ---------------------------------------------------------------------------
// K7: attn_h = tanh([c, source] @ W_out); c summed from the 4 k6 partials.
// ---------------------------------------------------------------------------
__global__ __launch_bounds__(256) void k7_out(
    const float* __restrict__ cpart, const float* __restrict__ src,
    const float* __restrict__ W, float* __restrict__ attn)
{
    const int b = blockIdx.y;
    const int t0 = blockIdx.x * 32;
    const int tid = threadIdx.x;
    const int tx = tid & 63, ty = tid >> 6;
    const size_t PSTRIDE = (size_t)BN * TT * DD;

    __shared__ __align__(16) float wT[32][256];
    __shared__ float xT[32][32];

    float4 acc[8];
#pragma unroll
    for (int i = 0; i < 8; i++) acc[i] = make_float4(0.f, 0.f, 0.f, 0.f);

    for (int k0 = 0; k0 < 2 * DD; k0 += 32) {
        __syncthreads();
#pragma unroll
        for (int it = 0; it < 8; it++) {
            int f = tid + it * 256;
            int kr = f >> 6, col = (f & 63) * 4;
            *(float4*)&wT[kr][col] =
                *(const float4*)(W + (size_t)(k0 + kr) * DD + col);
        }
#pragma unroll
        for (int rep = 0; rep < 4; rep++) {
            int idx = tid + rep * 256;
            int r = idx >> 5, c = idx & 31;
            int k = k0 + c;
            float x;
            if (k < DD) {
                const size_t ci = ((size_t)b * TT + t0 + r) * DD + k;
                x = cpart[ci] + cpart[ci + PSTRIDE] +
                    cpart[ci + 2 * PSTRIDE] + cpart[ci + 3 * PSTRIDE];
            } else {
                x = src[((size_t)b * TT + t0 + r) * DD + (k - DD)];
            }
            xT[r][c] = x;
        }
        __syncthreads();
#pragma unroll
        for (int kk = 0; kk < 32; kk++) {
            float4 w4 = *(const float4*)&wT[kk][tx * 4];
#pragma unroll
            for (int r4 = 0; r4 < 8; r4++) {
                float x = xT[ty + r4 * 4][kk];
                acc[r4].x += x * w4.x; acc[r4].y += x * w4.y;
                acc[r4].z += x * w4.z; acc[r4].w += x * w4.w;
            }
        }
    }
#pragma unroll
    for (int r4 = 0; r4 < 8; r4++) {
        const int t = t0 + ty + r4 * 4;
        float4 o;
        o.x = tanhf(acc[r4].x); o.y = tanhf(acc[r4].y);
        o.z = tanhf(acc[r4].z); o.w = tanhf(acc[r4].w);
        *(float4*)(attn + ((size_t)b * TT + t) * DD + tx * 4) = o;
    }
}

// ---------------------------------------------------------------------------
extern "C" void kernel_launch(void* const* d_in, const int* in_sizes, int n_in,
                              void* d_out, int out_size, void* d_ws, size_t ws_size,
                              hipStream_t stream)
{
    const float* src  = (const float*)d_in[0];   // [B,T,D]
    const float* mem  = (const float*)d_in[1];   // [B,S,D]
    const float* Wout = (const float*)d_in[2];   // [2D,D]
    const int*   lens = (const int*)d_in[3];     // [B]

    float* out    = (float*)d_out;
    float* attn   = out;                               // [B,T,D]
    float* alignb = out + (size_t)BN * TT * DD;        // [B,T,S] scratch -> final

    float* rowmax = (float*)d_ws;                                  // 64 KB
    float* segsum = rowmax + (size_t)BN * TT;                      // 4 MB
    unsigned short* mhi = (unsigned short*)(segsum + (size_t)BN * NSEG * SS); // 8 MB
    unsigned short* shi   = mhi + (size_t)BN * SS * DD;            // 8 MB (dead after k1)
    unsigned short* slo   = shi + (size_t)BN * TT * DD;            // 8 MB (dead after k1)
    unsigned short* mhirm = slo + (size_t)BN * TT * DD;            // 8 MB (dead after k1)
    unsigned short* mlorm = mhirm + (size_t)BN * SS * DD;          // 8 MB (dead after k1)
    float* cpart = (float*)shi;   // 64 MB, aliases k1-only bf16 buffers

    kpre<<<dim3(BN * TT * DD / (256 * 8), 2), 256, 0, stream>>>(
        src, mem, shi, slo, mhirm, mlorm);
    k6pre<<<dim3(BN * 64 * 16 * 64 / 256), 256, 0, stream>>>(mem, mhi);
    k1_mfma<<<dim3(SS / 128, TT / 128, BN), 256, 0, stream>>>(
        shi, slo, mhirm, mlorm, lens, alignb);
    k2_rowmax<<<dim3(BN * TT), 256, 0, stream>>>(alignb, lens, rowmax);
    k3_segsum<<<dim3(SS / 256, NSEG, BN), 256, 0, stream>>>(alignb, rowmax, lens, segsum);
    k4_prefix<<<dim3(SS / 256, BN), 256, 0, stream>>>(segsum);
    k5_scan<<<dim3(NSEG, BN), 256, 0, stream>>>(alignb, rowmax, segsum, lens);
    k6_context<<<dim3(BN, TT / 64, 4), 256, 0, stream>>>(alignb, mhi, lens, cpart);
    k7_out<<<dim3(TT / 32, BN), 256, 0, stream>>>(cpart, src, Wout, attn);
}